// Round 5
// baseline (1071.275 us; speedup 1.0000x reference)
//
#include <hip/hip_runtime.h>

// SSIM on (32,3,512,512) f32 — wave-autonomous separable 11-tap streaming.
// Each wave owns a 128-col x 64-row band: 64 lanes x 2 cols (packed v2f).
// No __syncthreads in hot loop (wave-private LDS row, same-wave DS order).
// R5: (a) all per-step math packed as 2-wide ext_vector float ops -> v_pk_*
// (colA,colB in one VGPR pair), halving VALU issue; (b) launch_bounds(256,4)
// so 768 blocks are fully co-resident (3 blocks/CU, 12 waves/CU).
// State remains 100% named scalars (R3 lesson: arrays -> scratch spills).

#define NBLK  768
#define NSTEP 74            // 10 warmup + 64 emitted rows

typedef float v2f __attribute__((ext_vector_type(2)));
#define V2Z ((v2f){0.f, 0.f})

#define DECL_ACC(S) v2f AX##S=V2Z, AY##S=V2Z, AXX##S=V2Z, AYY##S=V2Z, AXY##S=V2Z;

// One horizontal tap J for both columns: A uses val[J+1], B uses val[J+2].
#define HTAPP(J, XU, XV, YU, YV) { \
  const v2f gj = {g[J], g[J]}; \
  const v2f xp = {XU, XV}; const v2f yp = {YU, YV}; \
  const v2f t1 = gj * xp, t2 = gj * yp; \
  SX += t1; SY += t2; \
  SXX = __builtin_elementwise_fma(t1, xp, SXX); \
  SYY = __builtin_elementwise_fma(t2, yp, SYY); \
  SXY = __builtin_elementwise_fma(t1, yp, SXY); }

#define VACCP(S, RR) { const float wj = g[(10 - (S) + (RR)) % 11]; \
  const v2f w2 = {wj, wj}; \
  AX##S  = __builtin_elementwise_fma(w2, SX , AX##S ); \
  AY##S  = __builtin_elementwise_fma(w2, SY , AY##S ); \
  AXX##S = __builtin_elementwise_fma(w2, SXX, AXX##S); \
  AYY##S = __builtin_elementwise_fma(w2, SYY, AYY##S); \
  AXY##S = __builtin_elementwise_fma(w2, SXY, AXY##S); }

#define EMIT(S) { \
  { const float mux = AX##S.x, muy = AY##S.x; \
    const float mux2 = mux*mux, muy2 = muy*muy, muxy = mux*muy; \
    const float vvx = AXX##S.x - mux2, vvy = AYY##S.x - muy2, vxy = AXY##S.x - muxy; \
    const float num = fmaf(2.f, muxy, C1) * fmaf(2.f, vxy, C2); \
    const float den = (mux2 + muy2 + C1) * (vvx + vvy + C2); \
    ts.x += num * __builtin_amdgcn_rcpf(den); } \
  { const float mux = AX##S.y, muy = AY##S.y; \
    const float mux2 = mux*mux, muy2 = muy*muy, muxy = mux*muy; \
    const float vvx = AXX##S.y - mux2, vvy = AYY##S.y - muy2, vxy = AXY##S.y - muxy; \
    const float num = fmaf(2.f, muxy, C1) * fmaf(2.f, vxy, C2); \
    const float den = (mux2 + muy2 + C1) * (vvx + vvy + C2); \
    ts.y += num * __builtin_amdgcn_rcpf(den); } }

#define RESET(S) { AX##S=V2Z; AY##S=V2Z; AXX##S=V2Z; AYY##S=V2Z; AXY##S=V2Z; }

#define STEP(RR) { \
  const int i = ibase + (RR); \
  if (i < NSTEP) { \
    const int rn = r0 - 4 + i; \
    v2f mx=V2Z, my=V2Z, hx=V2Z, hy=V2Z; \
    if (i <= NSTEP-2 && (unsigned)rn < 512u) { \
      const float* xp = xplane + rn * 512; \
      const float* yp = yplane + rn * 512; \
      mx = *(const v2f*)(xp + mcol); my = *(const v2f*)(yp + mcol); \
      if (hOK) { hx = *(const v2f*)(xp + hcol); hy = *(const v2f*)(yp + hcol); } \
    } \
    const v2f xa0 = sxw[lane  ], xa1 = sxw[lane+1], xa2 = sxw[lane+2], xa3 = sxw[lane+3]; \
    const v2f xa4 = sxw[lane+4], xa5 = sxw[lane+5], xa6 = sxw[lane+6]; \
    const v2f ya0 = syw[lane  ], ya1 = syw[lane+1], ya2 = syw[lane+2], ya3 = syw[lane+3]; \
    const v2f ya4 = syw[lane+4], ya5 = syw[lane+5], ya6 = syw[lane+6]; \
    v2f SX=V2Z, SY=V2Z, SXX=V2Z, SYY=V2Z, SXY=V2Z; \
    HTAPP(0 , xa0.y, xa1.x, ya0.y, ya1.x) \
    HTAPP(1 , xa1.x, xa1.y, ya1.x, ya1.y) \
    HTAPP(2 , xa1.y, xa2.x, ya1.y, ya2.x) \
    HTAPP(3 , xa2.x, xa2.y, ya2.x, ya2.y) \
    HTAPP(4 , xa2.y, xa3.x, ya2.y, ya3.x) \
    HTAPP(5 , xa3.x, xa3.y, ya3.x, ya3.y) \
    HTAPP(6 , xa3.y, xa4.x, ya3.y, ya4.x) \
    HTAPP(7 , xa4.x, xa4.y, ya4.x, ya4.y) \
    HTAPP(8 , xa4.y, xa5.x, ya4.y, ya5.x) \
    HTAPP(9 , xa5.x, xa5.y, ya5.x, ya5.y) \
    HTAPP(10, xa5.y, xa6.x, ya5.y, ya6.x) \
    VACCP(0,RR) VACCP(1,RR) VACCP(2,RR) VACCP(3,RR) VACCP(4,RR) VACCP(5,RR) \
    VACCP(6,RR) VACCP(7,RR) VACCP(8,RR) VACCP(9,RR) VACCP(10,RR) \
    if (i >= 10) { EMIT(RR) } \
    RESET(RR) \
    sxw[lane+3] = mx; syw[lane+3] = my; \
    if (isHalo) { sxw[hslot] = hx; syw[hslot] = hy; } \
  } }

__global__ __launch_bounds__(256, 4) void ssim_fused(
    const float* __restrict__ x, const float* __restrict__ y,
    const float* __restrict__ window,
    unsigned* __restrict__ counter, float* __restrict__ partials,
    float* __restrict__ out)
{
    const int tid  = threadIdx.x;
    const int lane = tid & 63;
    const int wv   = tid >> 6;
    const int W    = blockIdx.x * 4 + wv;   // 0..3071
    const int img  = W >> 5;                // 96 planes
    const int cb   = (W >> 3) & 3;          // 4 col bands x 128
    const int rb   = W & 7;                 // 8 row bands x 64
    const int r0   = rb << 6;
    const int c0   = cb << 7;

    const float* xplane = x + (size_t)img * 262144;
    const float* yplane = y + (size_t)img * 262144;

    // 1-D gaussian: row i of outer(g,g) sums to g_i (sum(g)=1). Uniform.
    float g[11];
    #pragma unroll
    for (int ii = 0; ii < 11; ++ii) {
        float s = 0.f;
        #pragma unroll
        for (int jj = 0; jj < 11; ++jj) s += window[ii * 11 + jj];
        g[ii] = s;
    }

    // Wave-private LDS row: 70 v2f slots; slot k = cols c0-6+2k, +1.
    __shared__ v2f lsx[4][70];
    __shared__ v2f lsy[4][70];
    v2f* sxw = lsx[wv];
    v2f* syw = lsy[wv];

    const bool isHalo = lane < 6;
    const int  hslot  = (lane < 3) ? lane : (64 + lane);        // 0,1,2,67,68,69
    const int  hcol   = (lane < 3) ? (c0 - 6 + 2 * lane)
                                   : (c0 + 128 + 2 * (lane - 3));
    const bool hOK    = isHalo && (hcol >= 0) && (hcol < 511);
    const int  mcol   = c0 + 2 * lane;

    DECL_ACC(0) DECL_ACC(1) DECL_ACC(2) DECL_ACC(3) DECL_ACC(4) DECL_ACC(5)
    DECL_ACC(6) DECL_ACC(7) DECL_ACC(8) DECL_ACC(9) DECL_ACC(10)

    // Preload row r0-5 (zeros outside image).
    {
        const int rn = r0 - 5;
        v2f mx = V2Z, my = V2Z, hx = V2Z, hy = V2Z;
        if (rn >= 0) {
            const float* xp = xplane + rn * 512;
            const float* yp = yplane + rn * 512;
            mx = *(const v2f*)(xp + mcol);
            my = *(const v2f*)(yp + mcol);
            if (hOK) { hx = *(const v2f*)(xp + hcol); hy = *(const v2f*)(yp + hcol); }
        }
        sxw[lane + 3] = mx; syw[lane + 3] = my;
        if (isHalo) { sxw[hslot] = hx; syw[hslot] = hy; }
    }

    v2f ts = V2Z;
    const float C1 = 1e-4f, C2 = 9e-4f;

    #pragma unroll 1
    for (int chunk = 0; chunk < 7; ++chunk) {
        const int ibase = chunk * 11;
        STEP(0) STEP(1) STEP(2) STEP(3) STEP(4) STEP(5)
        STEP(6) STEP(7) STEP(8) STEP(9) STEP(10)
    }

    // ---- block partial: wave shuffle + cross-wave LDS ----
    float t = ts.x + ts.y;
    #pragma unroll
    for (int off = 32; off > 0; off >>= 1) t += __shfl_down(t, off, 64);
    __shared__ float wsum[4];
    __shared__ int   sflag;
    if (lane == 0) wsum[wv] = t;
    __syncthreads();
    if (tid == 0) {
        partials[blockIdx.x] = (wsum[0] + wsum[1]) + (wsum[2] + wsum[3]);
        __threadfence();
        const unsigned old = atomicAdd(counter, 1u);
        sflag = (old == NBLK - 1) ? 1 : 0;
    }
    __syncthreads();
    if (sflag) {                              // last block reduces everything
        __threadfence();
        double s = 0.0;
        for (int idx = tid; idx < NBLK; idx += 256) s += (double)partials[idx];
        #pragma unroll
        for (int off = 32; off > 0; off >>= 1) s += __shfl_down(s, off, 64);
        __shared__ double dsum[4];
        if (lane == 0) dsum[wv] = s;
        __syncthreads();
        if (tid == 0)
            out[0] = (float)(((dsum[0] + dsum[1]) + (dsum[2] + dsum[3])) / 25165824.0);
    }
}

extern "C" void kernel_launch(void* const* d_in, const int* in_sizes, int n_in,
                              void* d_out, int out_size, void* d_ws, size_t ws_size,
                              hipStream_t stream)
{
    const float* x = (const float*)d_in[0];
    const float* y = (const float*)d_in[1];
    const float* w = (const float*)d_in[2];
    unsigned* counter = (unsigned*)d_ws;                     // zeroed below
    float* partials   = (float*)((char*)d_ws + 256);         // 768 floats

    hipMemsetAsync(d_ws, 0, 4, stream);                      // capture-safe
    ssim_fused<<<NBLK, 256, 0, stream>>>(x, y, w, counter, partials, (float*)d_out);
}

// Round 6
// 369.974 us; speedup vs baseline: 2.8955x; 2.8955x over previous
//
#include <hip/hip_runtime.h>

// SSIM on (32,3,512,512) f32 — wave-autonomous separable 11-tap streaming.
// R6: 1-wave workgroups (block=64, grid=3072) for finest residency packing;
// gaussian weights forced to SGPRs via readfirstlane (frees ~11 VGPRs).
// Scalar math only — R5 proved packed v2f + VGPR cap 128 => full spill
// (WRITE_SIZE 1.5GB); R4 scalar landed at VGPR=128 with zero spill.
// Each wave owns a 128-col x 64-row band: 64 lanes x 2 cols.
// No barriers anywhere in the hot loop (wave-private LDS, same-wave DS order).
// Vertical conv: 11 rotating named float2 accumulators x 5 quantities; slot s
// gets weight g[(10-s+rr)%11] at step rr; emit+reset slot rr (R2-verified).

#define NBLK  3072
#define NSTEP 74            // 10 warmup + 64 emitted rows

__device__ __forceinline__ float2 f2z() { return make_float2(0.f, 0.f); }

#define DECL_ACC(S) float2 AX##S=f2z(), AY##S=f2z(), AXX##S=f2z(), AYY##S=f2z(), AXY##S=f2z();

#define HTAP(J, EA, EB) { const float gj = g##J; \
  { const float xv = x##EA, yv = y##EA; const float t1 = gj*xv, t2 = gj*yv; \
    sxA += t1; syA += t2; sxxA = fmaf(t1,xv,sxxA); syyA = fmaf(t2,yv,syyA); sxyA = fmaf(t1,yv,sxyA); } \
  { const float xv = x##EB, yv = y##EB; const float t1 = gj*xv, t2 = gj*yv; \
    sxB += t1; syB += t2; sxxB = fmaf(t1,xv,sxxB); syyB = fmaf(t2,yv,syyB); sxyB = fmaf(t1,yv,sxyB); } }

#define VACC1(S, GW) { const float wj = GW; \
  AX##S.x  = fmaf(wj, sxA , AX##S.x ); AX##S.y  = fmaf(wj, sxB , AX##S.y ); \
  AY##S.x  = fmaf(wj, syA , AY##S.x ); AY##S.y  = fmaf(wj, syB , AY##S.y ); \
  AXX##S.x = fmaf(wj, sxxA, AXX##S.x); AXX##S.y = fmaf(wj, sxxB, AXX##S.y); \
  AYY##S.x = fmaf(wj, syyA, AYY##S.x); AYY##S.y = fmaf(wj, syyB, AYY##S.y); \
  AXY##S.x = fmaf(wj, sxyA, AXY##S.x); AXY##S.y = fmaf(wj, sxyB, AXY##S.y); }

// VACC(S,RR): weight index (10 - S + RR) % 11, resolved to a named scalar.
#define VACC_IDX(S, K) VACC_IDX_##K(S)
#define VACC_IDX_0(S)  VACC1(S, g0)
#define VACC_IDX_1(S)  VACC1(S, g1)
#define VACC_IDX_2(S)  VACC1(S, g2)
#define VACC_IDX_3(S)  VACC1(S, g3)
#define VACC_IDX_4(S)  VACC1(S, g4)
#define VACC_IDX_5(S)  VACC1(S, g5)
#define VACC_IDX_6(S)  VACC1(S, g6)
#define VACC_IDX_7(S)  VACC1(S, g7)
#define VACC_IDX_8(S)  VACC1(S, g8)
#define VACC_IDX_9(S)  VACC1(S, g9)
#define VACC_IDX_10(S) VACC1(S, g10)

#define EMIT(S) { \
  { const float mux = AX##S.x, muy = AY##S.x; \
    const float mux2 = mux*mux, muy2 = muy*muy, muxy = mux*muy; \
    const float vvx = AXX##S.x - mux2, vvy = AYY##S.x - muy2, vxy = AXY##S.x - muxy; \
    const float num = fmaf(2.f, muxy, C1) * fmaf(2.f, vxy, C2); \
    const float den = (mux2 + muy2 + C1) * (vvx + vvy + C2); \
    tsx += num * __builtin_amdgcn_rcpf(den); } \
  { const float mux = AX##S.y, muy = AY##S.y; \
    const float mux2 = mux*mux, muy2 = muy*muy, muxy = mux*muy; \
    const float vvx = AXX##S.y - mux2, vvy = AYY##S.y - muy2, vxy = AXY##S.y - muxy; \
    const float num = fmaf(2.f, muxy, C1) * fmaf(2.f, vxy, C2); \
    const float den = (mux2 + muy2 + C1) * (vvx + vvy + C2); \
    tsy += num * __builtin_amdgcn_rcpf(den); } }

#define RESET(S) { AX##S=f2z(); AY##S=f2z(); AXX##S=f2z(); AYY##S=f2z(); AXY##S=f2z(); }

// One streaming step. RR = i % 11 (static slot), WJ* = weight names for VACC.
#define STEP(RR) { \
  const int i = ibase + (RR); \
  if (i < NSTEP) { \
    const int rn = r0 - 4 + i; \
    float2 mx=f2z(), my=f2z(), hx=f2z(), hy=f2z(); \
    if (i <= NSTEP-2 && (unsigned)rn < 512u) { \
      const float* xp = xplane + rn * 512; \
      const float* yp = yplane + rn * 512; \
      mx = *(const float2*)(xp + mcol); my = *(const float2*)(yp + mcol); \
      if (hOK) { hx = *(const float2*)(xp + hcol); hy = *(const float2*)(yp + hcol); } \
    } \
    const float2 xa0 = sxw[lane  ], xa1 = sxw[lane+1], xa2 = sxw[lane+2], xa3 = sxw[lane+3]; \
    const float2 xa4 = sxw[lane+4], xa5 = sxw[lane+5], xa6 = sxw[lane+6]; \
    const float2 ya0 = syw[lane  ], ya1 = syw[lane+1], ya2 = syw[lane+2], ya3 = syw[lane+3]; \
    const float2 ya4 = syw[lane+4], ya5 = syw[lane+5], ya6 = syw[lane+6]; \
    float sxA=0.f, syA=0.f, sxxA=0.f, syyA=0.f, sxyA=0.f; \
    float sxB=0.f, syB=0.f, sxxB=0.f, syyB=0.f, sxyB=0.f; \
    HTAP(0,a0.y,a1.x) HTAP(1,a1.x,a1.y) HTAP(2,a1.y,a2.x) HTAP(3,a2.x,a2.y) \
    HTAP(4,a2.y,a3.x) HTAP(5,a3.x,a3.y) HTAP(6,a3.y,a4.x) HTAP(7,a4.x,a4.y) \
    HTAP(8,a4.y,a5.x) HTAP(9,a5.x,a5.y) HTAP(10,a5.y,a6.x) \
    VACC_STEP_##RR \
    if (i >= 10) { EMIT(RR) } \
    RESET(RR) \
    sxw[lane+3] = mx; syw[lane+3] = my; \
    if (isHalo) { sxw[hslot] = hx; syw[hslot] = hy; } \
  } }

// VACC for all 11 slots at step rr: slot s uses weight (10-s+rr)%11.
#define VACC_STEP_0  VACC_IDX(0,10) VACC_IDX(1,9)  VACC_IDX(2,8)  VACC_IDX(3,7)  VACC_IDX(4,6)  VACC_IDX(5,5)  VACC_IDX(6,4)  VACC_IDX(7,3)  VACC_IDX(8,2)  VACC_IDX(9,1)  VACC_IDX(10,0)
#define VACC_STEP_1  VACC_IDX(0,0)  VACC_IDX(1,10) VACC_IDX(2,9)  VACC_IDX(3,8)  VACC_IDX(4,7)  VACC_IDX(5,6)  VACC_IDX(6,5)  VACC_IDX(7,4)  VACC_IDX(8,3)  VACC_IDX(9,2)  VACC_IDX(10,1)
#define VACC_STEP_2  VACC_IDX(0,1)  VACC_IDX(1,0)  VACC_IDX(2,10) VACC_IDX(3,9)  VACC_IDX(4,8)  VACC_IDX(5,7)  VACC_IDX(6,6)  VACC_IDX(7,5)  VACC_IDX(8,4)  VACC_IDX(9,3)  VACC_IDX(10,2)
#define VACC_STEP_3  VACC_IDX(0,2)  VACC_IDX(1,1)  VACC_IDX(2,0)  VACC_IDX(3,10) VACC_IDX(4,9)  VACC_IDX(5,8)  VACC_IDX(6,7)  VACC_IDX(7,6)  VACC_IDX(8,5)  VACC_IDX(9,4)  VACC_IDX(10,3)
#define VACC_STEP_4  VACC_IDX(0,3)  VACC_IDX(1,2)  VACC_IDX(2,1)  VACC_IDX(3,0)  VACC_IDX(4,10) VACC_IDX(5,9)  VACC_IDX(6,8)  VACC_IDX(7,7)  VACC_IDX(8,6)  VACC_IDX(9,5)  VACC_IDX(10,4)
#define VACC_STEP_5  VACC_IDX(0,4)  VACC_IDX(1,3)  VACC_IDX(2,2)  VACC_IDX(3,1)  VACC_IDX(4,0)  VACC_IDX(5,10) VACC_IDX(6,9)  VACC_IDX(7,8)  VACC_IDX(8,7)  VACC_IDX(9,6)  VACC_IDX(10,5)
#define VACC_STEP_6  VACC_IDX(0,5)  VACC_IDX(1,4)  VACC_IDX(2,3)  VACC_IDX(3,2)  VACC_IDX(4,1)  VACC_IDX(5,0)  VACC_IDX(6,10) VACC_IDX(7,9)  VACC_IDX(8,8)  VACC_IDX(9,7)  VACC_IDX(10,6)
#define VACC_STEP_7  VACC_IDX(0,6)  VACC_IDX(1,5)  VACC_IDX(2,4)  VACC_IDX(3,3)  VACC_IDX(4,2)  VACC_IDX(5,1)  VACC_IDX(6,0)  VACC_IDX(7,10) VACC_IDX(8,9)  VACC_IDX(9,8)  VACC_IDX(10,7)
#define VACC_STEP_8  VACC_IDX(0,7)  VACC_IDX(1,6)  VACC_IDX(2,5)  VACC_IDX(3,4)  VACC_IDX(4,3)  VACC_IDX(5,2)  VACC_IDX(6,1)  VACC_IDX(7,0)  VACC_IDX(8,10) VACC_IDX(9,9)  VACC_IDX(10,8)
#define VACC_STEP_9  VACC_IDX(0,8)  VACC_IDX(1,7)  VACC_IDX(2,6)  VACC_IDX(3,5)  VACC_IDX(4,4)  VACC_IDX(5,3)  VACC_IDX(6,2)  VACC_IDX(7,1)  VACC_IDX(8,0)  VACC_IDX(9,10) VACC_IDX(10,9)
#define VACC_STEP_10 VACC_IDX(0,9)  VACC_IDX(1,8)  VACC_IDX(2,7)  VACC_IDX(3,6)  VACC_IDX(4,5)  VACC_IDX(5,4)  VACC_IDX(6,3)  VACC_IDX(7,2)  VACC_IDX(8,1)  VACC_IDX(9,0)  VACC_IDX(10,10)

__global__ __launch_bounds__(64) void ssim_fused(
    const float* __restrict__ x, const float* __restrict__ y,
    const float* __restrict__ window,
    unsigned* __restrict__ counter, float* __restrict__ partials,
    float* __restrict__ out)
{
    const int lane = threadIdx.x;           // 0..63, one wave per block
    const int W    = blockIdx.x;            // 0..3071
    const int img  = W >> 5;                // 96 planes
    const int cb   = (W >> 3) & 3;          // 4 col bands x 128
    const int rb   = W & 7;                 // 8 row bands x 64
    const int r0   = rb << 6;
    const int c0   = cb << 7;

    const float* xplane = x + (size_t)img * 262144;
    const float* yplane = y + (size_t)img * 262144;

    // 1-D gaussian (row sums of outer(g,g)); forced into SGPRs.
    float gtmp[11];
    #pragma unroll
    for (int ii = 0; ii < 11; ++ii) {
        float s = 0.f;
        #pragma unroll
        for (int jj = 0; jj < 11; ++jj) s += window[ii * 11 + jj];
        gtmp[ii] = s;
    }
    #define SG(N) const float g##N = __uint_as_float(__builtin_amdgcn_readfirstlane(__float_as_uint(gtmp[N])));
    SG(0) SG(1) SG(2) SG(3) SG(4) SG(5) SG(6) SG(7) SG(8) SG(9) SG(10)

    // Wave-private LDS row: 70 float2 slots; slot k = cols c0-6+2k, +1.
    __shared__ float2 sxw[70];
    __shared__ float2 syw[70];

    const bool isHalo = lane < 6;
    const int  hslot  = (lane < 3) ? lane : (64 + lane);        // 0,1,2,67,68,69
    const int  hcol   = (lane < 3) ? (c0 - 6 + 2 * lane)
                                   : (c0 + 128 + 2 * (lane - 3));
    const bool hOK    = isHalo && (hcol >= 0) && (hcol < 511);
    const int  mcol   = c0 + 2 * lane;

    DECL_ACC(0) DECL_ACC(1) DECL_ACC(2) DECL_ACC(3) DECL_ACC(4) DECL_ACC(5)
    DECL_ACC(6) DECL_ACC(7) DECL_ACC(8) DECL_ACC(9) DECL_ACC(10)

    // Preload row r0-5 (zeros outside image).
    {
        const int rn = r0 - 5;
        float2 mx = f2z(), my = f2z(), hx = f2z(), hy = f2z();
        if (rn >= 0) {
            const float* xp = xplane + rn * 512;
            const float* yp = yplane + rn * 512;
            mx = *(const float2*)(xp + mcol);
            my = *(const float2*)(yp + mcol);
            if (hOK) { hx = *(const float2*)(xp + hcol); hy = *(const float2*)(yp + hcol); }
        }
        sxw[lane + 3] = mx; syw[lane + 3] = my;
        if (isHalo) { sxw[hslot] = hx; syw[hslot] = hy; }
    }

    float tsx = 0.f, tsy = 0.f;
    const float C1 = 1e-4f, C2 = 9e-4f;

    #pragma unroll 1
    for (int chunk = 0; chunk < 7; ++chunk) {
        const int ibase = chunk * 11;
        STEP(0) STEP(1) STEP(2) STEP(3) STEP(4) STEP(5)
        STEP(6) STEP(7) STEP(8) STEP(9) STEP(10)
    }

    // ---- wave partial -> global; last block reduces all ----
    float t = tsx + tsy;
    #pragma unroll
    for (int off = 32; off > 0; off >>= 1) t += __shfl_down(t, off, 64);
    unsigned old = 0u;
    if (lane == 0) {
        partials[W] = t;
        __threadfence();
        old = atomicAdd(counter, 1u);
    }
    old = __shfl(old, 0, 64);
    if (old == NBLK - 1) {
        __threadfence();
        double s = 0.0;
        for (int idx = lane; idx < NBLK; idx += 64) s += (double)partials[idx];
        #pragma unroll
        for (int off = 32; off > 0; off >>= 1) s += __shfl_down(s, off, 64);
        if (lane == 0) out[0] = (float)(s / 25165824.0);
    }
}

extern "C" void kernel_launch(void* const* d_in, const int* in_sizes, int n_in,
                              void* d_out, int out_size, void* d_ws, size_t ws_size,
                              hipStream_t stream)
{
    const float* x = (const float*)d_in[0];
    const float* y = (const float*)d_in[1];
    const float* w = (const float*)d_in[2];
    unsigned* counter = (unsigned*)d_ws;                     // zeroed below
    float* partials   = (float*)((char*)d_ws + 256);         // 3072 floats

    hipMemsetAsync(d_ws, 0, 4, stream);                      // capture-safe
    ssim_fused<<<NBLK, 64, 0, stream>>>(x, y, w, counter, partials, (float*)d_out);
}

// Round 7
// 359.199 us; speedup vs baseline: 2.9824x; 1.0300x over previous
//
#include <hip/hip_runtime.h>

// SSIM on (32,3,512,512) f32 — wave-autonomous separable 11-tap streaming.
// R7: depth-3 software-pipelined global prefetch. At step i we ISSUE the row
// needed at step i+3 into a named register ring PF0/PF1/PF2 (slot = i%3) and
// ds_write the row for step i+1 (issued at i-2) at step end — the vmcnt wait
// now covers ~3 step-walls instead of <1 (R6: 8000 cyc/step, VALUBusy 31%,
// HBM 464 GB/s => latency-bound convoy on same-step load consumption).
// Period = lcm(11 slots, 3 pf) = 33; 74 steps = 3 x 33 with i<74 guard.
// Everything else is the R4/R6-verified structure: 1-wave blocks (64 thr),
// wave-private LDS row (no barriers in hot loop), 11 rotating named float2
// accumulators x 5 quantities, emit+reset slot i%11 each step, SGPR weights.

#define NBLK  3072
#define NSTEP 74            // 10 warmup + 64 emitted rows

__device__ __forceinline__ float2 f2z() { return make_float2(0.f, 0.f); }

#define DECL_ACC(S) float2 AX##S=f2z(), AY##S=f2z(), AXX##S=f2z(), AYY##S=f2z(), AXY##S=f2z();

#define HTAP(J, EA, EB) { const float gj = g##J; \
  { const float xv = x##EA, yv = y##EA; const float t1 = gj*xv, t2 = gj*yv; \
    sxA += t1; syA += t2; sxxA = fmaf(t1,xv,sxxA); syyA = fmaf(t2,yv,syyA); sxyA = fmaf(t1,yv,sxyA); } \
  { const float xv = x##EB, yv = y##EB; const float t1 = gj*xv, t2 = gj*yv; \
    sxB += t1; syB += t2; sxxB = fmaf(t1,xv,sxxB); syyB = fmaf(t2,yv,syyB); sxyB = fmaf(t1,yv,sxyB); } }

#define VACC1(S, GW) { const float wj = GW; \
  AX##S.x  = fmaf(wj, sxA , AX##S.x ); AX##S.y  = fmaf(wj, sxB , AX##S.y ); \
  AY##S.x  = fmaf(wj, syA , AY##S.x ); AY##S.y  = fmaf(wj, syB , AY##S.y ); \
  AXX##S.x = fmaf(wj, sxxA, AXX##S.x); AXX##S.y = fmaf(wj, sxxB, AXX##S.y); \
  AYY##S.x = fmaf(wj, syyA, AYY##S.x); AYY##S.y = fmaf(wj, syyB, AYY##S.y); \
  AXY##S.x = fmaf(wj, sxyA, AXY##S.x); AXY##S.y = fmaf(wj, sxyB, AXY##S.y); }

#define VACC_IDX(S, K) VACC_IDX_##K(S)
#define VACC_IDX_0(S)  VACC1(S, g0)
#define VACC_IDX_1(S)  VACC1(S, g1)
#define VACC_IDX_2(S)  VACC1(S, g2)
#define VACC_IDX_3(S)  VACC1(S, g3)
#define VACC_IDX_4(S)  VACC1(S, g4)
#define VACC_IDX_5(S)  VACC1(S, g5)
#define VACC_IDX_6(S)  VACC1(S, g6)
#define VACC_IDX_7(S)  VACC1(S, g7)
#define VACC_IDX_8(S)  VACC1(S, g8)
#define VACC_IDX_9(S)  VACC1(S, g9)
#define VACC_IDX_10(S) VACC1(S, g10)

#define EMIT(S) { \
  { const float mux = AX##S.x, muy = AY##S.x; \
    const float mux2 = mux*mux, muy2 = muy*muy, muxy = mux*muy; \
    const float vvx = AXX##S.x - mux2, vvy = AYY##S.x - muy2, vxy = AXY##S.x - muxy; \
    const float num = fmaf(2.f, muxy, C1) * fmaf(2.f, vxy, C2); \
    const float den = (mux2 + muy2 + C1) * (vvx + vvy + C2); \
    tsx += num * __builtin_amdgcn_rcpf(den); } \
  { const float mux = AX##S.y, muy = AY##S.y; \
    const float mux2 = mux*mux, muy2 = muy*muy, muxy = mux*muy; \
    const float vvx = AXX##S.y - mux2, vvy = AYY##S.y - muy2, vxy = AXY##S.y - muxy; \
    const float num = fmaf(2.f, muxy, C1) * fmaf(2.f, vxy, C2); \
    const float den = (mux2 + muy2 + C1) * (vvx + vvy + C2); \
    tsy += num * __builtin_amdgcn_rcpf(den); } }

#define RESET(S) { AX##S=f2z(); AY##S=f2z(); AXX##S=f2z(); AYY##S=f2z(); AXY##S=f2z(); }

// VACC for all 11 slots at step rr: slot s uses weight g[(10-s+rr)%11].
#define VACC_STEP_0  VACC_IDX(0,10) VACC_IDX(1,9)  VACC_IDX(2,8)  VACC_IDX(3,7)  VACC_IDX(4,6)  VACC_IDX(5,5)  VACC_IDX(6,4)  VACC_IDX(7,3)  VACC_IDX(8,2)  VACC_IDX(9,1)  VACC_IDX(10,0)
#define VACC_STEP_1  VACC_IDX(0,0)  VACC_IDX(1,10) VACC_IDX(2,9)  VACC_IDX(3,8)  VACC_IDX(4,7)  VACC_IDX(5,6)  VACC_IDX(6,5)  VACC_IDX(7,4)  VACC_IDX(8,3)  VACC_IDX(9,2)  VACC_IDX(10,1)
#define VACC_STEP_2  VACC_IDX(0,1)  VACC_IDX(1,0)  VACC_IDX(2,10) VACC_IDX(3,9)  VACC_IDX(4,8)  VACC_IDX(5,7)  VACC_IDX(6,6)  VACC_IDX(7,5)  VACC_IDX(8,4)  VACC_IDX(9,3)  VACC_IDX(10,2)
#define VACC_STEP_3  VACC_IDX(0,2)  VACC_IDX(1,1)  VACC_IDX(2,0)  VACC_IDX(3,10) VACC_IDX(4,9)  VACC_IDX(5,8)  VACC_IDX(6,7)  VACC_IDX(7,6)  VACC_IDX(8,5)  VACC_IDX(9,4)  VACC_IDX(10,3)
#define VACC_STEP_4  VACC_IDX(0,3)  VACC_IDX(1,2)  VACC_IDX(2,1)  VACC_IDX(3,0)  VACC_IDX(4,10) VACC_IDX(5,9)  VACC_IDX(6,8)  VACC_IDX(7,7)  VACC_IDX(8,6)  VACC_IDX(9,5)  VACC_IDX(10,4)
#define VACC_STEP_5  VACC_IDX(0,4)  VACC_IDX(1,3)  VACC_IDX(2,2)  VACC_IDX(3,1)  VACC_IDX(4,0)  VACC_IDX(5,10) VACC_IDX(6,9)  VACC_IDX(7,8)  VACC_IDX(8,7)  VACC_IDX(9,6)  VACC_IDX(10,5)
#define VACC_STEP_6  VACC_IDX(0,5)  VACC_IDX(1,4)  VACC_IDX(2,3)  VACC_IDX(3,2)  VACC_IDX(4,1)  VACC_IDX(5,0)  VACC_IDX(6,10) VACC_IDX(7,9)  VACC_IDX(8,8)  VACC_IDX(9,7)  VACC_IDX(10,6)
#define VACC_STEP_7  VACC_IDX(0,6)  VACC_IDX(1,5)  VACC_IDX(2,4)  VACC_IDX(3,3)  VACC_IDX(4,2)  VACC_IDX(5,1)  VACC_IDX(6,0)  VACC_IDX(7,10) VACC_IDX(8,9)  VACC_IDX(9,8)  VACC_IDX(10,7)
#define VACC_STEP_8  VACC_IDX(0,7)  VACC_IDX(1,6)  VACC_IDX(2,5)  VACC_IDX(3,4)  VACC_IDX(4,3)  VACC_IDX(5,2)  VACC_IDX(6,1)  VACC_IDX(7,0)  VACC_IDX(8,10) VACC_IDX(9,9)  VACC_IDX(10,8)
#define VACC_STEP_9  VACC_IDX(0,8)  VACC_IDX(1,7)  VACC_IDX(2,6)  VACC_IDX(3,5)  VACC_IDX(4,4)  VACC_IDX(5,3)  VACC_IDX(6,2)  VACC_IDX(7,1)  VACC_IDX(8,0)  VACC_IDX(9,10) VACC_IDX(10,9)
#define VACC_STEP_10 VACC_IDX(0,9)  VACC_IDX(1,8)  VACC_IDX(2,7)  VACC_IDX(3,6)  VACC_IDX(4,5)  VACC_IDX(5,4)  VACC_IDX(6,3)  VACC_IDX(7,2)  VACC_IDX(8,1)  VACC_IDX(9,0)  VACC_IDX(10,10)

// One step. IDX in [0,33), RR = IDX%11, P = IDX%3 (issue slot), Q = (P+1)%3
// (slot written to LDS at step end — loaded 2 steps ago, waited 3 walls).
#define STEP(IDX, RR, P, Q) { \
  const int i = ibase + (IDX); \
  if (i < NSTEP) { \
    const int rl = r0 - 2 + i;                     /* row read at step i+3 */ \
    PF##P##mx = f2z(); PF##P##my = f2z(); PF##P##hx = f2z(); PF##P##hy = f2z(); \
    if (i < 71 && (unsigned)rl < 512u) { \
      const float* xp = xplane + rl * 512; \
      const float* yp = yplane + rl * 512; \
      PF##P##mx = *(const float2*)(xp + mcol); PF##P##my = *(const float2*)(yp + mcol); \
      if (hOK) { PF##P##hx = *(const float2*)(xp + hcol); PF##P##hy = *(const float2*)(yp + hcol); } \
    } \
    const float2 xa0 = sxw[lane  ], xa1 = sxw[lane+1], xa2 = sxw[lane+2], xa3 = sxw[lane+3]; \
    const float2 xa4 = sxw[lane+4], xa5 = sxw[lane+5], xa6 = sxw[lane+6]; \
    const float2 ya0 = syw[lane  ], ya1 = syw[lane+1], ya2 = syw[lane+2], ya3 = syw[lane+3]; \
    const float2 ya4 = syw[lane+4], ya5 = syw[lane+5], ya6 = syw[lane+6]; \
    float sxA=0.f, syA=0.f, sxxA=0.f, syyA=0.f, sxyA=0.f; \
    float sxB=0.f, syB=0.f, sxxB=0.f, syyB=0.f, sxyB=0.f; \
    HTAP(0,a0.y,a1.x) HTAP(1,a1.x,a1.y) HTAP(2,a1.y,a2.x) HTAP(3,a2.x,a2.y) \
    HTAP(4,a2.y,a3.x) HTAP(5,a3.x,a3.y) HTAP(6,a3.y,a4.x) HTAP(7,a4.x,a4.y) \
    HTAP(8,a4.y,a5.x) HTAP(9,a5.x,a5.y) HTAP(10,a5.y,a6.x) \
    VACC_STEP_##RR \
    if (i >= 10) { EMIT(RR) } \
    RESET(RR) \
    sxw[lane+3] = PF##Q##mx; syw[lane+3] = PF##Q##my; \
    if (isHalo) { sxw[hslot] = PF##Q##hx; syw[hslot] = PF##Q##hy; } \
  } }

#define CHUNK33 \
  STEP(0,0,0,1)   STEP(1,1,1,2)   STEP(2,2,2,0)   STEP(3,3,0,1)   STEP(4,4,1,2)   STEP(5,5,2,0) \
  STEP(6,6,0,1)   STEP(7,7,1,2)   STEP(8,8,2,0)   STEP(9,9,0,1)   STEP(10,10,1,2) \
  STEP(11,0,2,0)  STEP(12,1,0,1)  STEP(13,2,1,2)  STEP(14,3,2,0)  STEP(15,4,0,1)  STEP(16,5,1,2) \
  STEP(17,6,2,0)  STEP(18,7,0,1)  STEP(19,8,1,2)  STEP(20,9,2,0)  STEP(21,10,0,1) \
  STEP(22,0,1,2)  STEP(23,1,2,0)  STEP(24,2,0,1)  STEP(25,3,1,2)  STEP(26,4,2,0)  STEP(27,5,0,1) \
  STEP(28,6,1,2)  STEP(29,7,2,0)  STEP(30,8,0,1)  STEP(31,9,1,2)  STEP(32,10,2,0)

__global__ __launch_bounds__(64) void ssim_fused(
    const float* __restrict__ x, const float* __restrict__ y,
    const float* __restrict__ window,
    unsigned* __restrict__ counter, float* __restrict__ partials,
    float* __restrict__ out)
{
    const int lane = threadIdx.x;           // 0..63, one wave per block
    const int W    = blockIdx.x;            // 0..3071
    const int img  = W >> 5;                // 96 planes
    const int cb   = (W >> 3) & 3;          // 4 col bands x 128
    const int rb   = W & 7;                 // 8 row bands x 64
    const int r0   = rb << 6;
    const int c0   = cb << 7;

    const float* xplane = x + (size_t)img * 262144;
    const float* yplane = y + (size_t)img * 262144;

    const bool isHalo = lane < 6;
    const int  hslot  = (lane < 3) ? lane : (64 + lane);        // 0,1,2,67,68,69
    const int  hcol   = (lane < 3) ? (c0 - 6 + 2 * lane)
                                   : (c0 + 128 + 2 * (lane - 3));
    const bool hOK    = isHalo && (hcol >= 0) && (hcol < 511);
    const int  mcol   = c0 + 2 * lane;

    // --- prime the prefetch ring: PF1 <- row r0-4 (step 0 write),
    //     PF2 <- row r0-3 (step 1 write). Issued before anything else. ---
    float2 PF0mx, PF0my, PF0hx, PF0hy;
    float2 PF1mx = f2z(), PF1my = f2z(), PF1hx = f2z(), PF1hy = f2z();
    float2 PF2mx = f2z(), PF2my = f2z(), PF2hx = f2z(), PF2hy = f2z();
    if (r0 - 4 >= 0) {
        const float* xp = xplane + (r0 - 4) * 512;
        const float* yp = yplane + (r0 - 4) * 512;
        PF1mx = *(const float2*)(xp + mcol); PF1my = *(const float2*)(yp + mcol);
        if (hOK) { PF1hx = *(const float2*)(xp + hcol); PF1hy = *(const float2*)(yp + hcol); }
    }
    if (r0 - 3 >= 0) {
        const float* xp = xplane + (r0 - 3) * 512;
        const float* yp = yplane + (r0 - 3) * 512;
        PF2mx = *(const float2*)(xp + mcol); PF2my = *(const float2*)(yp + mcol);
        if (hOK) { PF2hx = *(const float2*)(xp + hcol); PF2hy = *(const float2*)(yp + hcol); }
    }

    // 1-D gaussian (row sums of outer(g,g)); forced into SGPRs.
    float gtmp[11];
    #pragma unroll
    for (int ii = 0; ii < 11; ++ii) {
        float s = 0.f;
        #pragma unroll
        for (int jj = 0; jj < 11; ++jj) s += window[ii * 11 + jj];
        gtmp[ii] = s;
    }
    #define SG(N) const float g##N = __uint_as_float(__builtin_amdgcn_readfirstlane(__float_as_uint(gtmp[N])));
    SG(0) SG(1) SG(2) SG(3) SG(4) SG(5) SG(6) SG(7) SG(8) SG(9) SG(10)

    // Wave-private LDS row: 70 float2 slots; slot k = cols c0-6+2k, +1.
    __shared__ float2 sxw[70];
    __shared__ float2 syw[70];

    DECL_ACC(0) DECL_ACC(1) DECL_ACC(2) DECL_ACC(3) DECL_ACC(4) DECL_ACC(5)
    DECL_ACC(6) DECL_ACC(7) DECL_ACC(8) DECL_ACC(9) DECL_ACC(10)

    // Preload LDS with row r0-5 (read at step 0); zeros outside image.
    {
        const int rn = r0 - 5;
        float2 mx = f2z(), my = f2z(), hx = f2z(), hy = f2z();
        if (rn >= 0) {
            const float* xp = xplane + rn * 512;
            const float* yp = yplane + rn * 512;
            mx = *(const float2*)(xp + mcol);
            my = *(const float2*)(yp + mcol);
            if (hOK) { hx = *(const float2*)(xp + hcol); hy = *(const float2*)(yp + hcol); }
        }
        sxw[lane + 3] = mx; syw[lane + 3] = my;
        if (isHalo) { sxw[hslot] = hx; syw[hslot] = hy; }
    }

    float tsx = 0.f, tsy = 0.f;
    const float C1 = 1e-4f, C2 = 9e-4f;

    #pragma unroll 1
    for (int it = 0; it < 3; ++it) {        // 3 x 33 steps, i<74 guarded
        const int ibase = it * 33;
        CHUNK33
    }

    // ---- wave partial -> global; last block reduces all ----
    float t = tsx + tsy;
    #pragma unroll
    for (int off = 32; off > 0; off >>= 1) t += __shfl_down(t, off, 64);
    unsigned old = 0u;
    if (lane == 0) {
        partials[W] = t;
        __threadfence();
        old = atomicAdd(counter, 1u);
    }
    old = __shfl(old, 0, 64);
    if (old == NBLK - 1) {
        __threadfence();
        double s = 0.0;
        for (int idx = lane; idx < NBLK; idx += 64) s += (double)partials[idx];
        #pragma unroll
        for (int off = 32; off > 0; off >>= 1) s += __shfl_down(s, off, 64);
        if (lane == 0) out[0] = (float)(s / 25165824.0);
    }
}

extern "C" void kernel_launch(void* const* d_in, const int* in_sizes, int n_in,
                              void* d_out, int out_size, void* d_ws, size_t ws_size,
                              hipStream_t stream)
{
    const float* x = (const float*)d_in[0];
    const float* y = (const float*)d_in[1];
    const float* w = (const float*)d_in[2];
    unsigned* counter = (unsigned*)d_ws;                     // zeroed below
    float* partials   = (float*)((char*)d_ws + 256);         // 3072 floats

    hipMemsetAsync(d_ws, 0, 4, stream);                      // capture-safe
    ssim_fused<<<NBLK, 64, 0, stream>>>(x, y, w, counter, partials, (float*)d_out);
}

// Round 8
// 282.444 us; speedup vs baseline: 3.7929x; 1.2718x over previous
//
#include <hip/hip_runtime.h>

// SSIM on (32,3,512,512) f32 — wave-autonomous separable 11-tap streaming.
// R8: (1) shift-register vertical conv (descending FMA chain, period-1 code,
// no rotation unroll -> ~8KB hot body); (2) fully branchless hot loop:
// unconditional clamped loads + multiply-by-validity at consume, so the
// waitcnt pass keeps precise vmcnt and the depth-3 register prefetch ring
// actually pipelines (R7's guarded loads forced vmcnt(0) every step);
// (3) LDS packed float4 (xA,xB,yA,yB) -> 7 ds_read_b128/step (was 14 b64);
// (4) 256-thread blocks = 4 wave-private bands sharing one I-stream.
// Each wave: 128 cols x 64 rows; lanes hold 2 cols. No hot-loop barriers.

#define NBLK 768

__device__ __forceinline__ float2 f2z() { return make_float2(0.f, 0.f); }
__device__ __forceinline__ float2 fma2(float s, float2 a, float2 c) {
    return make_float2(fmaf(s, a.x, c.x), fmaf(s, a.y, c.y));
}
__device__ __forceinline__ float2 mul2(float s, float2 a) {
    return make_float2(s * a.x, s * a.y);
}

// ---- vertical shift-register chains: 10 regs x 5 quantities (float2 A/B) ----
#define DECL_CH(C) float2 C##0=f2z(),C##1=f2z(),C##2=f2z(),C##3=f2z(),C##4=f2z(), \
                          C##5=f2z(),C##6=f2z(),C##7=f2z(),C##8=f2z(),C##9=f2z();
// descending: each reads the not-yet-overwritten lower element
#define SHIFT(C, H) \
  C##9 = fma2(g9, H, C##8); C##8 = fma2(g8, H, C##7); C##7 = fma2(g7, H, C##6); \
  C##6 = fma2(g6, H, C##5); C##5 = fma2(g5, H, C##4); C##4 = fma2(g4, H, C##3); \
  C##3 = fma2(g3, H, C##2); C##2 = fma2(g2, H, C##1); C##1 = fma2(g1, H, C##0); \
  C##0 = mul2(g0, H);

// ---- horizontal tap J: colA uses val[J+1], colB val[J+2] ----
#define HTAP(J, UA, UB) { const float gj = g##J; \
  { const float xv = XV##UA, yv = YV##UA; const float t1 = gj*xv, t2 = gj*yv; \
    HX.x += t1; HY.x += t2; HXX.x = fmaf(t1,xv,HXX.x); HYY.x = fmaf(t2,yv,HYY.x); HXY.x = fmaf(t1,yv,HXY.x); } \
  { const float xv = XV##UB, yv = YV##UB; const float t1 = gj*xv, t2 = gj*yv; \
    HX.y += t1; HY.y += t2; HXX.y = fmaf(t1,xv,HXX.y); HYY.y = fmaf(t2,yv,HYY.y); HXY.y = fmaf(t1,yv,HXY.y); } }

#define SSIM_COL(MU_X, MU_Y, SXX, SYY, SXY, TS) { \
  const float mux = MU_X, muy = MU_Y; \
  const float mux2 = mux*mux, muy2 = muy*muy, muxy = mux*muy; \
  const float vvx = SXX - mux2, vvy = SYY - muy2, vxy = SXY - muxy; \
  const float num = fmaf(2.f, muxy, C1) * fmaf(2.f, vxy, C2); \
  const float den = (mux2 + muy2 + C1) * (vvx + vvy + C2); \
  TS += num * __builtin_amdgcn_rcpf(den); }

// One step: issue PF slot P (row r0-2+i), compute h-conv of current LDS row,
// chain-shift, emit if 10<=i<74, then store PF slot Q (issued 2 steps ago).
#define STEP(I, P, Q) { \
  const int i_ = (I); \
  const int rl = r0 - 2 + i_; \
  VM##P = ((unsigned)rl < 512u) ? 1.f : 0.f; \
  { const int rlc = (rl < 0) ? 0 : ((rl > 511) ? 511 : rl); \
    const float* xp = xplane + (rlc << 9); \
    const float* yp = yplane + (rlc << 9); \
    PF##P##mx = *(const float2*)(xp + mcol); PF##P##my = *(const float2*)(yp + mcol); \
    PF##P##hx = *(const float2*)(xp + hcolC); PF##P##hy = *(const float2*)(yp + hcolC); } \
  const float4 q0 = lsw[lane  ], q1 = lsw[lane+1], q2 = lsw[lane+2], q3 = lsw[lane+3]; \
  const float4 q4 = lsw[lane+4], q5 = lsw[lane+5], q6 = lsw[lane+6]; \
  const float XV1 = q0.y, XV2 = q1.x, XV3 = q1.y, XV4 = q2.x, XV5 = q2.y, XV6 = q3.x; \
  const float XV7 = q3.y, XV8 = q4.x, XV9 = q4.y, XV10 = q5.x, XV11 = q5.y, XV12 = q6.x; \
  const float YV1 = q0.w, YV2 = q1.z, YV3 = q1.w, YV4 = q2.z, YV5 = q2.w, YV6 = q3.z; \
  const float YV7 = q3.w, YV8 = q4.z, YV9 = q4.w, YV10 = q5.z, YV11 = q5.w, YV12 = q6.z; \
  float2 HX = f2z(), HY = f2z(), HXX = f2z(), HYY = f2z(), HXY = f2z(); \
  HTAP(0,1,2)  HTAP(1,2,3)  HTAP(2,3,4)  HTAP(3,4,5)  HTAP(4,5,6)  HTAP(5,6,7) \
  HTAP(6,7,8)  HTAP(7,8,9)  HTAP(8,9,10) HTAP(9,10,11) HTAP(10,11,12) \
  if (i_ >= 10 && i_ < 74) { \
    const float2 EX  = fma2(g10, HX , CX9 ); \
    const float2 EY  = fma2(g10, HY , CY9 ); \
    const float2 EXX = fma2(g10, HXX, CXX9); \
    const float2 EYY = fma2(g10, HYY, CYY9); \
    const float2 EXY = fma2(g10, HXY, CXY9); \
    SSIM_COL(EX.x, EY.x, EXX.x, EYY.x, EXY.x, tsx) \
    SSIM_COL(EX.y, EY.y, EXX.y, EYY.y, EXY.y, tsy) \
  } \
  SHIFT(CX, HX) SHIFT(CY, HY) SHIFT(CXX, HXX) SHIFT(CYY, HYY) SHIFT(CXY, HXY) \
  { const float fq = VM##Q; const float fh = fq * hmask; \
    const float2 wmx = mul2(fq, PF##Q##mx), wmy = mul2(fq, PF##Q##my); \
    const float2 whx = mul2(fh, PF##Q##hx), why = mul2(fh, PF##Q##hy); \
    lsw[lane + 3] = make_float4(wmx.x, wmx.y, wmy.x, wmy.y); \
    if (lane < 6) lsw[hslot] = make_float4(whx.x, whx.y, why.x, why.y); } }

__global__ __launch_bounds__(256, 2) void ssim_fused(
    const float* __restrict__ x, const float* __restrict__ y,
    const float* __restrict__ window,
    unsigned* __restrict__ counter, float* __restrict__ partials,
    float* __restrict__ out)
{
    const int tid  = threadIdx.x;
    const int lane = tid & 63;
    const int wv   = tid >> 6;
    const int W    = blockIdx.x * 4 + wv;   // 0..3071
    const int img  = W >> 5;                // 96 planes
    const int cb   = (W >> 3) & 3;          // 4 col bands x 128
    const int rb   = W & 7;                 // 8 row bands x 64
    const int r0   = rb << 6;
    const int c0   = cb << 7;

    const float* xplane = x + (size_t)img * 262144;
    const float* yplane = y + (size_t)img * 262144;

    // halo geometry (time-invariant): slots 0..2 left, 67..69 right
    const int  hslot = (lane < 3) ? lane : (64 + lane);
    const int  hcol  = (lane < 3) ? (c0 - 6 + 2 * lane)
                                  : (c0 + 128 + 2 * (lane - 3));
    const float hmask = (lane < 6 && hcol >= 0 && hcol < 511) ? 1.f : 0.f;
    const int  hcolC = (hcol < 0) ? 0 : ((hcol > 510) ? 510 : hcol);
    const int  mcol  = c0 + 2 * lane;

    // 1-D gaussian (row sums of outer(g,g)); uniform -> SGPR via readfirstlane
    float gtmp[11];
    #pragma unroll
    for (int ii = 0; ii < 11; ++ii) {
        float s = 0.f;
        #pragma unroll
        for (int jj = 0; jj < 11; ++jj) s += window[ii * 11 + jj];
        gtmp[ii] = s;
    }
    #define SG(N) const float g##N = __uint_as_float(__builtin_amdgcn_readfirstlane(__float_as_uint(gtmp[N])));
    SG(0) SG(1) SG(2) SG(3) SG(4) SG(5) SG(6) SG(7) SG(8) SG(9) SG(10)

    // wave-private LDS row: slot k = float4(xA,xB,yA,yB) for cols c0-6+2k,+1
    __shared__ float4 ls4[4][72];
    float4* lsw = ls4[wv];

    DECL_CH(CX) DECL_CH(CY) DECL_CH(CXX) DECL_CH(CYY) DECL_CH(CXY)

    // prefetch ring state
    float2 PF0mx, PF0my, PF0hx, PF0hy; float VM0 = 0.f;
    float2 PF1mx, PF1my, PF1hx, PF1hy; float VM1;
    float2 PF2mx, PF2my, PF2hx, PF2hy; float VM2;

    // prime LDS with row r0-5 (read at step 0)
    {
        const int rl = r0 - 5;
        const float fq = ((unsigned)rl < 512u) ? 1.f : 0.f;
        const int rlc = (rl < 0) ? 0 : rl;
        const float* xp = xplane + (rlc << 9);
        const float* yp = yplane + (rlc << 9);
        const float2 mx = *(const float2*)(xp + mcol), my = *(const float2*)(yp + mcol);
        const float2 hx = *(const float2*)(xp + hcolC), hy = *(const float2*)(yp + hcolC);
        const float fh = fq * hmask;
        const float2 wmx = mul2(fq, mx), wmy = mul2(fq, my);
        const float2 whx = mul2(fh, hx), why = mul2(fh, hy);
        lsw[lane + 3] = make_float4(wmx.x, wmx.y, wmy.x, wmy.y);
        if (lane < 6) lsw[hslot] = make_float4(whx.x, whx.y, why.x, why.y);
    }
    // prime PF1 <- row r0-4 (stored end of step 0), PF2 <- row r0-3 (step 1)
    {
        const int rl = r0 - 4;
        VM1 = ((unsigned)rl < 512u) ? 1.f : 0.f;
        const int rlc = (rl < 0) ? 0 : rl;
        const float* xp = xplane + (rlc << 9);
        const float* yp = yplane + (rlc << 9);
        PF1mx = *(const float2*)(xp + mcol); PF1my = *(const float2*)(yp + mcol);
        PF1hx = *(const float2*)(xp + hcolC); PF1hy = *(const float2*)(yp + hcolC);
    }
    {
        const int rl = r0 - 3;
        VM2 = ((unsigned)rl < 512u) ? 1.f : 0.f;
        const int rlc = (rl < 0) ? 0 : rl;
        const float* xp = xplane + (rlc << 9);
        const float* yp = yplane + (rlc << 9);
        PF2mx = *(const float2*)(xp + mcol); PF2my = *(const float2*)(yp + mcol);
        PF2hx = *(const float2*)(xp + hcolC); PF2hy = *(const float2*)(yp + hcolC);
    }

    float tsx = 0.f, tsy = 0.f;
    const float C1 = 1e-4f, C2 = 9e-4f;

    // 75 steps = 25 x 3 (PF ring period); emits for i in [10,74)
    #pragma unroll 1
    for (int it = 0; it < 25; ++it) {
        const int i0 = it * 3;
        STEP(i0 + 0, 0, 1)
        STEP(i0 + 1, 1, 2)
        STEP(i0 + 2, 2, 0)
    }

    // ---- block partial -> global; last block reduces all ----
    float t = tsx + tsy;
    #pragma unroll
    for (int off = 32; off > 0; off >>= 1) t += __shfl_down(t, off, 64);
    __shared__ float wsum[4];
    __shared__ int   sflag;
    if (lane == 0) wsum[wv] = t;
    __syncthreads();
    if (tid == 0) {
        partials[blockIdx.x] = (wsum[0] + wsum[1]) + (wsum[2] + wsum[3]);
        __threadfence();
        const unsigned old = atomicAdd(counter, 1u);
        sflag = (old == NBLK - 1) ? 1 : 0;
    }
    __syncthreads();
    if (sflag) {
        __threadfence();
        double s = 0.0;
        for (int idx = tid; idx < NBLK; idx += 256) s += (double)partials[idx];
        #pragma unroll
        for (int off = 32; off > 0; off >>= 1) s += __shfl_down(s, off, 64);
        __shared__ double dsum[4];
        if (lane == 0) dsum[wv] = s;
        __syncthreads();
        if (tid == 0)
            out[0] = (float)(((dsum[0] + dsum[1]) + (dsum[2] + dsum[3])) / 25165824.0);
    }
}

extern "C" void kernel_launch(void* const* d_in, const int* in_sizes, int n_in,
                              void* d_out, int out_size, void* d_ws, size_t ws_size,
                              hipStream_t stream)
{
    const float* x = (const float*)d_in[0];
    const float* y = (const float*)d_in[1];
    const float* w = (const float*)d_in[2];
    unsigned* counter = (unsigned*)d_ws;                     // zeroed below
    float* partials   = (float*)((char*)d_ws + 256);         // 768 floats

    hipMemsetAsync(d_ws, 0, 4, stream);                      // capture-safe
    ssim_fused<<<NBLK, 256, 0, stream>>>(x, y, w, counter, partials, (float*)d_out);
}